// Round 1
// baseline (3507.541 us; speedup 1.0000x reference)
//
#include <hip/hip_runtime.h>
#include <math.h>

#define D_MODEL 1024
#define N_SEQ   4096
#define N_HEADS 16
#define DHEAD   64
#define QKV_COLS 3072   // 3 * 1024

// ---------------- LayerNorm: one block per row ----------------
__global__ __launch_bounds__(256) void ln_kernel(const float* __restrict__ x,
                                                 const float* __restrict__ g,
                                                 const float* __restrict__ b,
                                                 float* __restrict__ h) {
    int row = blockIdx.x;
    int t = threadIdx.x;
    float4 v = ((const float4*)(x + (size_t)row * D_MODEL))[t];
    float s  = v.x + v.y + v.z + v.w;
    float ss = v.x*v.x + v.y*v.y + v.z*v.z + v.w*v.w;
    for (int off = 32; off; off >>= 1) {
        s  += __shfl_down(s, off);
        ss += __shfl_down(ss, off);
    }
    __shared__ float sm[4], ssm[4];
    __shared__ float mu_s, rs_s;
    int wave = t >> 6, lane = t & 63;
    if (lane == 0) { sm[wave] = s; ssm[wave] = ss; }
    __syncthreads();
    if (t == 0) {
        float S = 0.f, SS = 0.f;
        for (int w = 0; w < 4; w++) { S += sm[w]; SS += ssm[w]; }
        float mu = S / D_MODEL;
        float var = SS / D_MODEL - mu * mu;
        mu_s = mu;
        rs_s = rsqrtf(var + 1e-5f);
    }
    __syncthreads();
    float mu = mu_s, rs = rs_s;
    float4 gv = ((const float4*)g)[t];
    float4 bv = ((const float4*)b)[t];
    float4 o;
    o.x = (v.x - mu) * rs * gv.x + bv.x;
    o.y = (v.y - mu) * rs * gv.y + bv.y;
    o.z = (v.z - mu) * rs * gv.z + bv.z;
    o.w = (v.w - mu) * rs * gv.w + bv.w;
    ((float4*)(h + (size_t)row * D_MODEL))[t] = o;
}

// ---------------- fp32 tiled GEMM: C[M,N] = A[M,K] * B[K,N] ----------------
// BM=BN=64, BK=16, 256 threads, 4x4 micro-tile per thread.
__global__ __launch_bounds__(256) void gemm_kernel(const float* __restrict__ A,
                                                   const float* __restrict__ B,
                                                   float* __restrict__ C,
                                                   int M, int N, int K) {
    __shared__ float As[16][68];
    __shared__ float Bs[16][68];
    int t = threadIdx.x;
    int tx = t & 15, ty = t >> 4;
    int m0 = blockIdx.x * 64, n0 = blockIdx.y * 64;
    int am = t >> 2, ak = (t & 3) * 4;     // A: row m0+am, cols k0+ak..+3
    int bk = t >> 4, bn = (t & 15) * 4;    // B: row k0+bk, cols n0+bn..+3
    float acc[4][4] = {};
    for (int k0 = 0; k0 < K; k0 += 16) {
        float4 av = *(const float4*)(A + (size_t)(m0 + am) * K + k0 + ak);
        As[ak + 0][am] = av.x;
        As[ak + 1][am] = av.y;
        As[ak + 2][am] = av.z;
        As[ak + 3][am] = av.w;
        *(float4*)&Bs[bk][bn] = *(const float4*)(B + (size_t)(k0 + bk) * N + n0 + bn);
        __syncthreads();
#pragma unroll
        for (int k = 0; k < 16; k++) {
            float4 a4 = *(const float4*)&As[k][ty * 4];
            float4 b4 = *(const float4*)&Bs[k][tx * 4];
            float aa[4] = {a4.x, a4.y, a4.z, a4.w};
            float bb[4] = {b4.x, b4.y, b4.z, b4.w};
#pragma unroll
            for (int i = 0; i < 4; i++)
#pragma unroll
                for (int j = 0; j < 4; j++)
                    acc[i][j] += aa[i] * bb[j];
        }
        __syncthreads();
    }
#pragma unroll
    for (int i = 0; i < 4; i++) {
        float4 o = {acc[i][0], acc[i][1], acc[i][2], acc[i][3]};
        *(float4*)(C + (size_t)(m0 + ty * 4 + i) * N + n0 + tx * 4) = o;
    }
}

// ---------------- cache write (pre-RoPE k,v) + in-place RoPE on q,k --------
__global__ __launch_bounds__(256) void rope_cache_kernel(float* __restrict__ qkv,
                                                         float* __restrict__ out_k,
                                                         float* __restrict__ out_v) {
    int n = blockIdx.x;
    int t = threadIdx.x;
    float* row = qkv + (size_t)n * QKV_COLS;
    // 512 rotation pairs for q and k each
    for (int p = t; p < 512; p += 256) {
        int hd = p >> 5;       // head 0..15
        int i  = p & 31;       // pair index 0..31
        float inv_freq = powf(10000.0f, -(float)(2 * i) / 64.0f);
        float ang = (float)n * inv_freq;
        float sv, cv;
        sincosf(ang, &sv, &cv);
        int c0 = hd * 64 + 2 * i;
        // q (in place)
        float q0 = row[c0], q1 = row[c0 + 1];
        row[c0]     = q0 * cv - q1 * sv;
        row[c0 + 1] = q1 * cv + q0 * sv;
        // k: write pre-RoPE cache, then rope in place
        float k0 = row[1024 + c0], k1 = row[1024 + c0 + 1];
        size_t kidx = ((size_t)hd * N_SEQ + n) * 64 + 2 * i;
        out_k[kidx]     = k0;
        out_k[kidx + 1] = k1;
        row[1024 + c0]     = k0 * cv - k1 * sv;
        row[1024 + c0 + 1] = k1 * cv + k0 * sv;
    }
    // v copy to [h, n, dh] cache layout
    for (int m = t; m < 1024; m += 256) {
        int hd = m >> 6, dh = m & 63;
        out_v[((size_t)hd * N_SEQ + n) * 64 + dh] = row[2048 + m];
    }
}

// ---------------- flash-style causal attention ----------------
// grid (qtile=64, head=16), 64 threads (1 wave). Thread r owns q-row qt*64+r.
__global__ __launch_bounds__(64) void flash_kernel(const float* __restrict__ qkv,
                                                   const float* __restrict__ v_cache,
                                                   float* __restrict__ attn_out) {
    int qt = blockIdx.x;
    int h  = blockIdx.y;
    int r  = threadIdx.x;
    int qi = qt * 64 + r;

    const float* qrow = qkv + (size_t)qi * QKV_COLS + h * 64;
    float q[64];
#pragma unroll
    for (int d = 0; d < 64; d += 4) {
        float4 t4 = *(const float4*)(qrow + d);
        q[d] = t4.x; q[d + 1] = t4.y; q[d + 2] = t4.z; q[d + 3] = t4.w;
    }
    float O[64];
#pragma unroll
    for (int d = 0; d < 64; d++) O[d] = 0.f;
    float m = -INFINITY, l = 0.f;

    __shared__ float Kt[64][64];
    __shared__ float Vt[64][64];

    int kend = qt * 64;
    for (int k0 = 0; k0 <= kend; k0 += 64) {
        __syncthreads();
        // cooperative load of K-tile (roped k in qkv) and V-tile (v cache)
        for (int jj = 0; jj < 64; jj += 4) {
            int j  = jj + (r >> 4);
            int d4 = (r & 15) * 4;
            *(float4*)&Kt[j][d4] =
                *(const float4*)(qkv + (size_t)(k0 + j) * QKV_COLS + 1024 + h * 64 + d4);
            *(float4*)&Vt[j][d4] =
                *(const float4*)(v_cache + ((size_t)h * N_SEQ + k0 + j) * 64 + d4);
        }
        __syncthreads();
        bool diag = (k0 == kend);
#pragma unroll 1
        for (int jc = 0; jc < 64; jc += 16) {
            float s[16];
            float mc = -INFINITY;
#pragma unroll
            for (int jj = 0; jj < 16; jj++) {
                int j = jc + jj;
                float dot = 0.f;
#pragma unroll
                for (int d = 0; d < 64; d += 4) {
                    float4 kv = *(const float4*)&Kt[j][d];
                    dot += q[d] * kv.x + q[d + 1] * kv.y + q[d + 2] * kv.z + q[d + 3] * kv.w;
                }
                dot *= 0.125f;
                if (diag && (k0 + j > qi)) dot = -INFINITY;
                s[jj] = dot;
                mc = fmaxf(mc, dot);
            }
            if (mc == -INFINITY) continue;  // fully masked chunk
            float mnew  = fmaxf(m, mc);
            float alpha = __expf(m - mnew);  // exp(-inf)=0 on first hit
            float lc = 0.f;
#pragma unroll
            for (int jj = 0; jj < 16; jj++) {
                s[jj] = __expf(s[jj] - mnew);  // exp(-inf)=0 for masked
                lc += s[jj];
            }
            l = l * alpha + lc;
#pragma unroll
            for (int d = 0; d < 64; d++) O[d] *= alpha;
#pragma unroll
            for (int jj = 0; jj < 16; jj++) {
                float pj = s[jj];
#pragma unroll
                for (int d = 0; d < 64; d += 4) {
                    float4 vv = *(const float4*)&Vt[jc + jj][d];
                    O[d]     += pj * vv.x;
                    O[d + 1] += pj * vv.y;
                    O[d + 2] += pj * vv.z;
                    O[d + 3] += pj * vv.w;
                }
            }
            m = mnew;
        }
    }
    float inv_l = 1.0f / l;
    float* orow = attn_out + (size_t)qi * 1024 + h * 64;
#pragma unroll
    for (int d = 0; d < 64; d += 4) {
        float4 o = {O[d] * inv_l, O[d + 1] * inv_l, O[d + 2] * inv_l, O[d + 3] * inv_l};
        *(float4*)(orow + d) = o;
    }
}

extern "C" void kernel_launch(void* const* d_in, const int* in_sizes, int n_in,
                              void* d_out, int out_size, void* d_ws, size_t ws_size,
                              hipStream_t stream) {
    const float* x     = (const float*)d_in[0];
    const float* w_qkv = (const float*)d_in[1];
    const float* w_out = (const float*)d_in[2];
    const float* ln_g  = (const float*)d_in[3];
    const float* ln_b  = (const float*)d_in[4];

    float* out   = (float*)d_out;                       // [4096,1024]
    float* out_k = (float*)d_out + 4194304;             // [16,4096,64]
    float* out_v = (float*)d_out + 8388608;             // [16,4096,64]

    float* ws   = (float*)d_ws;
    float* h    = ws;                                   // 4096*1024
    float* qkv  = ws + 4194304;                         // 4096*3072
    float* attn = ws + 16777216;                        // 4096*1024

    // 1. LayerNorm
    ln_kernel<<<N_SEQ, 256, 0, stream>>>(x, ln_g, ln_b, h);
    // 2. QKV projection: [4096,1024] @ [1024,3072]
    gemm_kernel<<<dim3(64, 48), 256, 0, stream>>>(h, w_qkv, qkv, N_SEQ, QKV_COLS, D_MODEL);
    // 3. cache write + RoPE
    rope_cache_kernel<<<N_SEQ, 256, 0, stream>>>(qkv, out_k, out_v);
    // 4. causal flash attention
    flash_kernel<<<dim3(64, 16), 64, 0, stream>>>(qkv, out_v, attn);
    // 5. output projection: [4096,1024] @ [1024,1024]
    gemm_kernel<<<dim3(64, 16), 256, 0, stream>>>(attn, w_out, out, N_SEQ, D_MODEL, D_MODEL);
}

// Round 2
// 432.613 us; speedup vs baseline: 8.1078x; 8.1078x over previous
//
#include <hip/hip_runtime.h>
#include <math.h>

#define D_MODEL 1024
#define N_SEQ   4096
#define N_HEADS 16
#define DHEAD   64
#define QKV_COLS 3072   // 3 * 1024

typedef short bf16x8 __attribute__((ext_vector_type(8)));
typedef float f32x4  __attribute__((ext_vector_type(4)));

static __device__ __forceinline__ unsigned short f2bf(float f) {
    union { float f; unsigned u; } v; v.f = f;
    unsigned r = (v.u + 0x7fffu + ((v.u >> 16) & 1u)) >> 16;
    return (unsigned short)r;
}

// ---------------- LayerNorm: one block per row, bf16 out ----------------
__global__ __launch_bounds__(256) void ln_kernel(const float* __restrict__ x,
                                                 const float* __restrict__ g,
                                                 const float* __restrict__ b,
                                                 unsigned short* __restrict__ h) {
    int row = blockIdx.x;
    int t = threadIdx.x;
    float4 v = ((const float4*)(x + (size_t)row * D_MODEL))[t];
    float s  = v.x + v.y + v.z + v.w;
    float ss = v.x*v.x + v.y*v.y + v.z*v.z + v.w*v.w;
    for (int off = 32; off; off >>= 1) {
        s  += __shfl_down(s, off);
        ss += __shfl_down(ss, off);
    }
    __shared__ float sm[4], ssm[4];
    __shared__ float mu_s, rs_s;
    int wave = t >> 6, lane = t & 63;
    if (lane == 0) { sm[wave] = s; ssm[wave] = ss; }
    __syncthreads();
    if (t == 0) {
        float S = 0.f, SS = 0.f;
        for (int w = 0; w < 4; w++) { S += sm[w]; SS += ssm[w]; }
        float mu = S / D_MODEL;
        float var = SS / D_MODEL - mu * mu;
        mu_s = mu;
        rs_s = rsqrtf(var + 1e-5f);
    }
    __syncthreads();
    float mu = mu_s, rs = rs_s;
    float4 gv = ((const float4*)g)[t];
    float4 bv = ((const float4*)b)[t];
    ushort4 o;
    o.x = f2bf((v.x - mu) * rs * gv.x + bv.x);
    o.y = f2bf((v.y - mu) * rs * gv.y + bv.y);
    o.z = f2bf((v.z - mu) * rs * gv.z + bv.z);
    o.w = f2bf((v.w - mu) * rs * gv.w + bv.w);
    *(ushort4*)(h + (size_t)row * D_MODEL + t * 4) = o;
}

// ------------- transpose + fp32->bf16: W[K][N] -> Wt[N][K] -------------
__global__ __launch_bounds__(256) void transpose_cvt(const float* __restrict__ W,
                                                     unsigned short* __restrict__ Wt,
                                                     int K, int N) {
    __shared__ float tile[64][65];
    int k0 = blockIdx.x * 64, n0 = blockIdx.y * 64;
    int t = threadIdx.x;
#pragma unroll
    for (int p = 0; p < 16; p++) {
        int idx = p * 256 + t;
        int r = idx >> 6, c = idx & 63;
        tile[r][c] = W[(size_t)(k0 + r) * N + n0 + c];
    }
    __syncthreads();
#pragma unroll
    for (int p = 0; p < 16; p++) {
        int idx = p * 256 + t;
        int r2 = idx >> 6, c2 = idx & 63;   // r2: n-local, c2: k-local
        Wt[(size_t)(n0 + r2) * K + k0 + c2] = f2bf(tile[c2][r2]);
    }
}

// ------------- MFMA bf16 GEMM: C[M,N] = A[M,K] * Bt[N,K]^T, fp32 out ---
// block 256 thr (4 waves), tile 64x64, BK=32
__global__ __launch_bounds__(256) void gemm_bt(const unsigned short* __restrict__ A,
                                               const unsigned short* __restrict__ Bt,
                                               float* __restrict__ C,
                                               int M, int N, int K) {
    __shared__ unsigned short As[64 * 40];
    __shared__ unsigned short Bs[64 * 40];
    int t = threadIdx.x;
    int w = t >> 6, lane = t & 63;
    int l16 = lane & 15, quad = lane >> 4;
    int m0 = blockIdx.x * 64, n0 = blockIdx.y * 64;
    int srow = t >> 2, skc = (t & 3) * 8;

    f32x4 acc[4];
#pragma unroll
    for (int tt = 0; tt < 4; tt++) acc[tt] = (f32x4){0.f, 0.f, 0.f, 0.f};

    for (int k0 = 0; k0 < K; k0 += 32) {
        __syncthreads();
        *(bf16x8*)(&As[srow * 40 + skc]) =
            *(const bf16x8*)(A + (size_t)(m0 + srow) * K + k0 + skc);
        *(bf16x8*)(&Bs[srow * 40 + skc]) =
            *(const bf16x8*)(Bt + (size_t)(n0 + srow) * K + k0 + skc);
        __syncthreads();
        bf16x8 a = *(const bf16x8*)(&As[(w * 16 + l16) * 40 + quad * 8]);
#pragma unroll
        for (int tt = 0; tt < 4; tt++) {
            bf16x8 b = *(const bf16x8*)(&Bs[(tt * 16 + l16) * 40 + quad * 8]);
            acc[tt] = __builtin_amdgcn_mfma_f32_16x16x32_bf16(a, b, acc[tt], 0, 0, 0);
        }
    }
#pragma unroll
    for (int tt = 0; tt < 4; tt++)
#pragma unroll
        for (int r = 0; r < 4; r++)
            C[(size_t)(m0 + w * 16 + quad * 4 + r) * N + n0 + tt * 16 + l16] = acc[tt][r];
}

// --------- cache write (pre-RoPE k,v fp32) + RoPE + bf16 emit ----------
__global__ __launch_bounds__(256) void rope_cache_kernel(const float* __restrict__ qkv,
                                                         float* __restrict__ out_k,
                                                         float* __restrict__ out_v,
                                                         unsigned short* __restrict__ q_bf,
                                                         unsigned short* __restrict__ k_bf,
                                                         unsigned short* __restrict__ vt_bf) {
    int n = blockIdx.x;
    int t = threadIdx.x;
    const float* row = qkv + (size_t)n * QKV_COLS;
    for (int p = t; p < 512; p += 256) {
        int hd = p >> 5;
        int i  = p & 31;
        float inv_freq = powf(10000.0f, -(float)(2 * i) / 64.0f);
        float ang = (float)n * inv_freq;
        float sv, cv;
        sincosf(ang, &sv, &cv);
        int c0 = hd * 64 + 2 * i;
        size_t base = ((size_t)hd * N_SEQ + n) * 64 + 2 * i;
        // q roped -> bf16
        float q0 = row[c0], q1 = row[c0 + 1];
        q_bf[base]     = f2bf(q0 * cv - q1 * sv);
        q_bf[base + 1] = f2bf(q1 * cv + q0 * sv);
        // k: pre-RoPE fp32 cache, roped bf16
        float k0 = row[1024 + c0], k1 = row[1024 + c0 + 1];
        out_k[base]     = k0;
        out_k[base + 1] = k1;
        k_bf[base]     = f2bf(k0 * cv - k1 * sv);
        k_bf[base + 1] = f2bf(k1 * cv + k0 * sv);
    }
    for (int m = t; m < 1024; m += 256) {
        int hd = m >> 6, dh = m & 63;
        float v = row[2048 + m];
        out_v[((size_t)hd * N_SEQ + n) * 64 + dh] = v;
        vt_bf[((size_t)hd * 64 + dh) * N_SEQ + n] = f2bf(v);   // transposed
    }
}

// ---------------- MFMA flash attention (causal) ----------------
// grid (64 qtiles, 16 heads) x 256 thr. Wave w owns q-rows qt*64+w*16..+15.
__global__ __launch_bounds__(256) void flash_mfma(const unsigned short* __restrict__ q_bf,
                                                  const unsigned short* __restrict__ k_bf,
                                                  const unsigned short* __restrict__ vt_bf,
                                                  unsigned short* __restrict__ attn_bf) {
    int qt = 63 - blockIdx.x;          // heavy (long-k) blocks first
    int h  = blockIdx.y;
    int t  = threadIdx.x;
    int w  = t >> 6, lane = t & 63;
    int l16 = lane & 15, quad = lane >> 4;

    __shared__ unsigned short Ks[64 * 72];
    __shared__ unsigned short Vs[64 * 72];   // transposed: row=d, col=kpos
    __shared__ unsigned short Ps[4 * 16 * 72];

    int qr0 = qt * 64 + w * 16;
    bf16x8 aq[2];
    {
        const unsigned short* qp = q_bf + ((size_t)h * N_SEQ + qr0 + l16) * 64 + quad * 8;
        aq[0] = *(const bf16x8*)(qp);
        aq[1] = *(const bf16x8*)(qp + 32);
    }
    f32x4 O[4];
#pragma unroll
    for (int dt = 0; dt < 4; dt++) O[dt] = (f32x4){0.f, 0.f, 0.f, 0.f};
    float m_r[4], l_r[4];
#pragma unroll
    for (int r = 0; r < 4; r++) { m_r[r] = -1e30f; l_r[r] = 0.f; }

    for (int kt = 0; kt <= qt; kt++) {
        int k0 = kt * 64;
        __syncthreads();
        {
            int chunk = t;
#pragma unroll
            for (int p = 0; p < 2; p++, chunk += 256) {
                int row = chunk >> 3, c8 = (chunk & 7) * 8;
                *(bf16x8*)(&Ks[row * 72 + c8]) =
                    *(const bf16x8*)(k_bf + ((size_t)h * N_SEQ + k0 + row) * 64 + c8);
                *(bf16x8*)(&Vs[row * 72 + c8]) =
                    *(const bf16x8*)(vt_bf + ((size_t)h * 64 + row) * N_SEQ + k0 + c8);
            }
        }
        __syncthreads();

        bool diag = (kt == qt);
        f32x4 s[4];
#pragma unroll
        for (int tt = 0; tt < 4; tt++) {
            f32x4 a4 = (f32x4){0.f, 0.f, 0.f, 0.f};
            if (!diag || tt <= w) {
                const unsigned short* kp = &Ks[(tt * 16 + l16) * 72 + quad * 8];
                bf16x8 b0 = *(const bf16x8*)(kp);
                bf16x8 b1 = *(const bf16x8*)(kp + 32);
                a4 = __builtin_amdgcn_mfma_f32_16x16x32_bf16(aq[0], b0, a4, 0, 0, 0);
                a4 = __builtin_amdgcn_mfma_f32_16x16x32_bf16(aq[1], b1, a4, 0, 0, 0);
            }
            s[tt] = a4;
        }
        float p_f[4][4];
        float rowmax[4];
#pragma unroll
        for (int r = 0; r < 4; r++) rowmax[r] = -1e30f;
#pragma unroll
        for (int tt = 0; tt < 4; tt++) {
            bool skip_tile = diag && (tt > w);
#pragma unroll
            for (int r = 0; r < 4; r++) {
                float v = s[tt][r] * 0.125f;
                if (skip_tile || (diag && (tt * 16 + l16 > w * 16 + quad * 4 + r))) v = -1e30f;
                p_f[tt][r] = v;
                rowmax[r] = fmaxf(rowmax[r], v);
            }
        }
        unsigned short* pw = &Ps[w * 16 * 72];
#pragma unroll
        for (int r = 0; r < 4; r++) {
            float rm = rowmax[r];
            rm = fmaxf(rm, __shfl_xor(rm, 1));
            rm = fmaxf(rm, __shfl_xor(rm, 2));
            rm = fmaxf(rm, __shfl_xor(rm, 4));
            rm = fmaxf(rm, __shfl_xor(rm, 8));
            float mnew  = fmaxf(m_r[r], rm);
            float alpha = __expf(m_r[r] - mnew);
            m_r[r] = mnew;
            float rs = 0.f;
#pragma unroll
            for (int tt = 0; tt < 4; tt++) {
                float p = __expf(p_f[tt][r] - mnew);
                p_f[tt][r] = p;
                rs += p;
            }
            rs += __shfl_xor(rs, 1);
            rs += __shfl_xor(rs, 2);
            rs += __shfl_xor(rs, 4);
            rs += __shfl_xor(rs, 8);
            l_r[r] = l_r[r] * alpha + rs;
#pragma unroll
            for (int dt = 0; dt < 4; dt++) O[dt][r] *= alpha;
        }
        // P: C-layout regs -> bf16 LDS (per-wave region), read back in A-layout
#pragma unroll
        for (int tt = 0; tt < 4; tt++)
#pragma unroll
            for (int r = 0; r < 4; r++)
                pw[(quad * 4 + r) * 72 + tt * 16 + l16] = f2bf(p_f[tt][r]);
#pragma unroll
        for (int c = 0; c < 2; c++) {
            bf16x8 ap = *(const bf16x8*)(&pw[l16 * 72 + c * 32 + quad * 8]);
#pragma unroll
            for (int dt = 0; dt < 4; dt++) {
                bf16x8 bv = *(const bf16x8*)(&Vs[(dt * 16 + l16) * 72 + c * 32 + quad * 8]);
                O[dt] = __builtin_amdgcn_mfma_f32_16x16x32_bf16(ap, bv, O[dt], 0, 0, 0);
            }
        }
    }
#pragma unroll
    for (int r = 0; r < 4; r++) {
        float inv = 1.0f / l_r[r];
        unsigned short* op = attn_bf + (size_t)(qr0 + quad * 4 + r) * D_MODEL + h * 64;
#pragma unroll
        for (int dt = 0; dt < 4; dt++)
            op[dt * 16 + l16] = f2bf(O[dt][r] * inv);
    }
}

extern "C" void kernel_launch(void* const* d_in, const int* in_sizes, int n_in,
                              void* d_out, int out_size, void* d_ws, size_t ws_size,
                              hipStream_t stream) {
    const float* x     = (const float*)d_in[0];
    const float* w_qkv = (const float*)d_in[1];
    const float* w_out = (const float*)d_in[2];
    const float* ln_g  = (const float*)d_in[3];
    const float* ln_b  = (const float*)d_in[4];

    float* out   = (float*)d_out;                       // [4096,1024]
    float* out_k = (float*)d_out + 4194304;             // [16,4096,64]
    float* out_v = (float*)d_out + 8388608;             // [16,4096,64]

    char* ws = (char*)d_ws;
    const size_t MiB = 1048576;
    float*          qkv_f   = (float*)(ws);                    // [4096,3072] fp32   @0..48MiB
    unsigned short* h_bf    = (unsigned short*)(ws + 48*MiB);  // [4096,1024] bf16   @48..56 (dead after gemm1)
    unsigned short* wqkvT   = (unsigned short*)(ws + 56*MiB);  // [3072,1024] bf16   @56..62 (dead after gemm1)
    unsigned short* q_bf    = (unsigned short*)(ws + 48*MiB);  // [16,4096,64] bf16  @48..56 (after gemm1)
    unsigned short* k_bf    = (unsigned short*)(ws + 56*MiB);  // [16,4096,64] bf16  @56..64
    unsigned short* vt_bf   = (unsigned short*)(ws + 64*MiB);  // [16,64,4096] bf16  @64..72
    unsigned short* attn_bf = (unsigned short*)(ws);           // [4096,1024] bf16   @0..8 (after rope)
    unsigned short* woutT   = (unsigned short*)(ws + 72*MiB);  // [1024,1024] bf16   @72..74

    // weights: transpose + bf16
    transpose_cvt<<<dim3(16, 48), 256, 0, stream>>>(w_qkv, wqkvT, D_MODEL, QKV_COLS);
    transpose_cvt<<<dim3(16, 16), 256, 0, stream>>>(w_out, woutT, D_MODEL, D_MODEL);
    // LN -> bf16
    ln_kernel<<<N_SEQ, 256, 0, stream>>>(x, ln_g, ln_b, h_bf);
    // qkv = h @ w_qkv  (fp32 out for exact-ish caches)
    gemm_bt<<<dim3(64, 48), 256, 0, stream>>>(h_bf, wqkvT, qkv_f, N_SEQ, QKV_COLS, D_MODEL);
    // caches + rope + bf16 per-head layouts
    rope_cache_kernel<<<N_SEQ, 256, 0, stream>>>(qkv_f, out_k, out_v, q_bf, k_bf, vt_bf);
    // causal flash attention (MFMA)
    flash_mfma<<<dim3(64, 16), 256, 0, stream>>>(q_bf, k_bf, vt_bf, attn_bf);
    // out = attn @ w_out
    gemm_bt<<<dim3(64, 16), 256, 0, stream>>>(attn_bf, woutT, out, N_SEQ, D_MODEL, D_MODEL);
}

// Round 3
// 341.279 us; speedup vs baseline: 10.2776x; 1.2676x over previous
//
#include <hip/hip_runtime.h>
#include <math.h>

#define D_MODEL 1024
#define N_SEQ   4096
#define N_HEADS 16
#define DHEAD   64
#define QKV_COLS 3072   // 3 * 1024

typedef short bf16x8 __attribute__((ext_vector_type(8)));
typedef float f32x4  __attribute__((ext_vector_type(4)));

static __device__ __forceinline__ unsigned short f2bf(float f) {
    union { float f; unsigned u; } v; v.f = f;
    unsigned r = (v.u + 0x7fffu + ((v.u >> 16) & 1u)) >> 16;
    return (unsigned short)r;
}

typedef __attribute__((address_space(1))) const void* gas_t;
typedef __attribute__((address_space(3))) void* las_t;
static __device__ __forceinline__ void load_lds16(const unsigned short* g, unsigned short* l) {
    __builtin_amdgcn_global_load_lds((gas_t)g, (las_t)l, 16, 0, 0);
}

// ---------------- LayerNorm: one block per row, bf16 out ----------------
__global__ __launch_bounds__(256) void ln_kernel(const float* __restrict__ x,
                                                 const float* __restrict__ g,
                                                 const float* __restrict__ b,
                                                 unsigned short* __restrict__ h) {
    int row = blockIdx.x;
    int t = threadIdx.x;
    float4 v = ((const float4*)(x + (size_t)row * D_MODEL))[t];
    float s  = v.x + v.y + v.z + v.w;
    float ss = v.x*v.x + v.y*v.y + v.z*v.z + v.w*v.w;
    for (int off = 32; off; off >>= 1) {
        s  += __shfl_down(s, off);
        ss += __shfl_down(ss, off);
    }
    __shared__ float sm[4], ssm[4];
    __shared__ float mu_s, rs_s;
    int wave = t >> 6, lane = t & 63;
    if (lane == 0) { sm[wave] = s; ssm[wave] = ss; }
    __syncthreads();
    if (t == 0) {
        float S = 0.f, SS = 0.f;
        for (int w = 0; w < 4; w++) { S += sm[w]; SS += ssm[w]; }
        float mu = S / D_MODEL;
        float var = SS / D_MODEL - mu * mu;
        mu_s = mu;
        rs_s = rsqrtf(var + 1e-5f);
    }
    __syncthreads();
    float mu = mu_s, rs = rs_s;
    float4 gv = ((const float4*)g)[t];
    float4 bv = ((const float4*)b)[t];
    ushort4 o;
    o.x = f2bf((v.x - mu) * rs * gv.x + bv.x);
    o.y = f2bf((v.y - mu) * rs * gv.y + bv.y);
    o.z = f2bf((v.z - mu) * rs * gv.z + bv.z);
    o.w = f2bf((v.w - mu) * rs * gv.w + bv.w);
    *(ushort4*)(h + (size_t)row * D_MODEL + t * 4) = o;
}

// ------------- transpose + fp32->bf16: W[K][N] -> Wt[N][K] -------------
__global__ __launch_bounds__(256) void transpose_cvt(const float* __restrict__ W,
                                                     unsigned short* __restrict__ Wt,
                                                     int K, int N) {
    __shared__ float tile[64][65];
    int k0 = blockIdx.x * 64, n0 = blockIdx.y * 64;
    int t = threadIdx.x;
#pragma unroll
    for (int p = 0; p < 16; p++) {
        int idx = p * 256 + t;
        int r = idx >> 6, c = idx & 63;
        tile[r][c] = W[(size_t)(k0 + r) * N + n0 + c];
    }
    __syncthreads();
#pragma unroll
    for (int p = 0; p < 16; p++) {
        int idx = p * 256 + t;
        int r2 = idx >> 6, c2 = idx & 63;   // r2: n-local, c2: k-local
        Wt[(size_t)(n0 + r2) * K + k0 + c2] = f2bf(tile[c2][r2]);
    }
}

// ---- m97-style MFMA bf16 GEMM: C[M,N] = A[M,K] * Bt[N,K]^T, fp32 out ----
// 128x128 tile, BK=32, 256 thr (4 waves, 2x2), global_load_lds width-16 staging.
__global__ __launch_bounds__(256) void gemm_bt128(const unsigned short* __restrict__ A,
                                                  const unsigned short* __restrict__ Bt,
                                                  float* __restrict__ C,
                                                  int M, int N, int K) {
    __shared__ unsigned short As[128 * 32];
    __shared__ unsigned short Bs[128 * 32];
    int t = threadIdx.x;
    int w = t >> 6, lane = t & 63;
    int l16 = lane & 15, quad = lane >> 4;
    int wr = w >> 1, wc = w & 1;
    int m0 = blockIdx.x * 128, n0 = blockIdx.y * 128;
    int srow = lane >> 2, scol = (lane & 3) * 8;
    int c0 = w * 2, c1 = c0 + 1;

    f32x4 acc[4][4] = {};

    for (int k0 = 0; k0 < K; k0 += 32) {
        __syncthreads();
        load_lds16(A  + (size_t)(m0 + c0 * 16 + srow) * K + k0 + scol, &As[c0 * 512 + lane * 8]);
        load_lds16(A  + (size_t)(m0 + c1 * 16 + srow) * K + k0 + scol, &As[c1 * 512 + lane * 8]);
        load_lds16(Bt + (size_t)(n0 + c0 * 16 + srow) * K + k0 + scol, &Bs[c0 * 512 + lane * 8]);
        load_lds16(Bt + (size_t)(n0 + c1 * 16 + srow) * K + k0 + scol, &Bs[c1 * 512 + lane * 8]);
        __syncthreads();
        bf16x8 a[4], b[4];
#pragma unroll
        for (int mt = 0; mt < 4; mt++)
            a[mt] = *(const bf16x8*)&As[(wr * 64 + mt * 16 + l16) * 32 + quad * 8];
#pragma unroll
        for (int nt = 0; nt < 4; nt++)
            b[nt] = *(const bf16x8*)&Bs[(wc * 64 + nt * 16 + l16) * 32 + quad * 8];
#pragma unroll
        for (int mt = 0; mt < 4; mt++)
#pragma unroll
            for (int nt = 0; nt < 4; nt++)
                acc[mt][nt] = __builtin_amdgcn_mfma_f32_16x16x32_bf16(a[mt], b[nt], acc[mt][nt], 0, 0, 0);
    }
#pragma unroll
    for (int mt = 0; mt < 4; mt++)
#pragma unroll
        for (int nt = 0; nt < 4; nt++)
#pragma unroll
            for (int r = 0; r < 4; r++)
                C[(size_t)(m0 + wr * 64 + mt * 16 + quad * 4 + r) * N + n0 + wc * 64 + nt * 16 + l16] =
                    acc[mt][nt][r];
}

// --------- cache write (pre-RoPE k,v fp32) + RoPE + bf16 emit ----------
__global__ __launch_bounds__(256) void rope_cache_kernel(const float* __restrict__ qkv,
                                                         float* __restrict__ out_k,
                                                         float* __restrict__ out_v,
                                                         unsigned short* __restrict__ q_bf,
                                                         unsigned short* __restrict__ k_bf,
                                                         unsigned short* __restrict__ vt_bf) {
    int n = blockIdx.x;
    int t = threadIdx.x;
    const float* row = qkv + (size_t)n * QKV_COLS;
    for (int p = t; p < 512; p += 256) {
        int hd = p >> 5;
        int i  = p & 31;
        float inv_freq = powf(10000.0f, -(float)(2 * i) / 64.0f);
        float ang = (float)n * inv_freq;
        float sv, cv;
        sincosf(ang, &sv, &cv);
        int c0 = hd * 64 + 2 * i;
        size_t base = ((size_t)hd * N_SEQ + n) * 64 + 2 * i;
        float q0 = row[c0], q1 = row[c0 + 1];
        q_bf[base]     = f2bf(q0 * cv - q1 * sv);
        q_bf[base + 1] = f2bf(q1 * cv + q0 * sv);
        float k0 = row[1024 + c0], k1 = row[1024 + c0 + 1];
        out_k[base]     = k0;
        out_k[base + 1] = k1;
        k_bf[base]     = f2bf(k0 * cv - k1 * sv);
        k_bf[base + 1] = f2bf(k1 * cv + k0 * sv);
    }
    for (int m = t; m < 1024; m += 256) {
        int hd = m >> 6, dh = m & 63;
        float v = row[2048 + m];
        out_v[((size_t)hd * N_SEQ + n) * 64 + dh] = v;
        vt_bf[((size_t)hd * 64 + dh) * N_SEQ + n] = f2bf(v);   // transposed
    }
}

// ---------------- MFMA flash attention (causal, S^T form) ----------------
// grid (64 qtiles, 16 heads) x 256 thr. Wave w owns q-cols qt*64+w*16..+15.
// S^T = K*Q^T (keys in rows), static softmax (no running max), O^T accum.
__global__ __launch_bounds__(256) void flash_mfma(const unsigned short* __restrict__ q_bf,
                                                  const unsigned short* __restrict__ k_bf,
                                                  const unsigned short* __restrict__ vt_bf,
                                                  unsigned short* __restrict__ attn_bf) {
    int qt = 63 - blockIdx.x;          // heavy (long-k) blocks first
    int h  = blockIdx.y;
    int t  = threadIdx.x;
    int w  = t >> 6, lane = t & 63;
    int l16 = lane & 15, quad = lane >> 4;

    __shared__ unsigned short Ks[64 * 72];
    __shared__ unsigned short Vs[64 * 72];   // transposed: row=d, col=kpos
    __shared__ unsigned short Ps[4 * 16 * 72];
    unsigned short* pw = &Ps[w * 16 * 72];   // per-wave P[q16][keys64+pad]

    int qr0 = qt * 64 + w * 16;
    // Q as B-operand frag: B[k=d][n=q]: lane n=l16 -> q row l16, k=quad*8+j
    bf16x8 bq[2];
    {
        const unsigned short* qp = q_bf + ((size_t)h * N_SEQ + qr0 + l16) * 64 + quad * 8;
        bq[0] = *(const bf16x8*)(qp);
        bq[1] = *(const bf16x8*)(qp + 32);
    }
    f32x4 O[4];   // O^T tiles: row d=dt*16+quad*4+r, col q=l16
#pragma unroll
    for (int dt = 0; dt < 4; dt++) O[dt] = (f32x4){0.f, 0.f, 0.f, 0.f};
    float lp = 0.f;   // per-lane partial softmax denominator for q=l16

    int srow = t >> 3, sc8 = (t & 7) * 8;
    for (int kt = 0; kt <= qt; kt++) {
        int k0 = kt * 64;
        __syncthreads();
        *(bf16x8*)&Ks[srow * 72 + sc8] =
            *(const bf16x8*)(k_bf + ((size_t)h * N_SEQ + k0 + srow) * 64 + sc8);
        *(bf16x8*)&Vs[srow * 72 + sc8] =
            *(const bf16x8*)(vt_bf + ((size_t)h * 64 + srow) * N_SEQ + k0 + sc8);
        *(bf16x8*)&Ks[(srow + 32) * 72 + sc8] =
            *(const bf16x8*)(k_bf + ((size_t)h * N_SEQ + k0 + srow + 32) * 64 + sc8);
        *(bf16x8*)&Vs[(srow + 32) * 72 + sc8] =
            *(const bf16x8*)(vt_bf + ((size_t)h * 64 + srow + 32) * N_SEQ + k0 + sc8);
        __syncthreads();

        bool diag = (kt == qt);
#pragma unroll
        for (int tt = 0; tt < 4; tt++) {
            ushort4 pk = {0, 0, 0, 0};
            if (!diag || tt <= w) {
                f32x4 s = (f32x4){0.f, 0.f, 0.f, 0.f};
                const unsigned short* kp = &Ks[(tt * 16 + l16) * 72 + quad * 8];
                bf16x8 ka = *(const bf16x8*)(kp);
                bf16x8 kb = *(const bf16x8*)(kp + 32);
                // S^T tile: A=K (rows=keys), B=Q^T (cols=q)
                s = __builtin_amdgcn_mfma_f32_16x16x32_bf16(ka, bq[0], s, 0, 0, 0);
                s = __builtin_amdgcn_mfma_f32_16x16x32_bf16(kb, bq[1], s, 0, 0, 0);
                unsigned short pr[4];
#pragma unroll
                for (int r = 0; r < 4; r++) {
                    float p = __expf(s[r] * 0.125f);
                    if (diag && (tt * 16 + quad * 4 + r > w * 16 + l16)) p = 0.f;
                    lp += p;
                    pr[r] = f2bf(p);
                }
                pk.x = pr[0]; pk.y = pr[1]; pk.z = pr[2]; pk.w = pr[3];
            }
            // lane holds keys tt*16+quad*4..+3 for q=l16 -> one b64 write
            *(ushort4*)&pw[l16 * 72 + tt * 16 + quad * 4] = pk;
        }
        // O^T += V^T * P^T : A=V^T from Vs, B=P^T read as P[q][key] rows
#pragma unroll
        for (int c = 0; c < 2; c++) {
            bf16x8 pb = *(const bf16x8*)&pw[l16 * 72 + c * 32 + quad * 8];
#pragma unroll
            for (int dt = 0; dt < 4; dt++) {
                bf16x8 va = *(const bf16x8*)&Vs[(dt * 16 + l16) * 72 + c * 32 + quad * 8];
                O[dt] = __builtin_amdgcn_mfma_f32_16x16x32_bf16(va, pb, O[dt], 0, 0, 0);
            }
        }
    }
    // finalize l: sum the 4 quad partials for q=l16
    lp += __shfl_xor(lp, 16);
    lp += __shfl_xor(lp, 32);
    float inv = 1.0f / lp;
#pragma unroll
    for (int dt = 0; dt < 4; dt++) {
        ushort4 o;
        o.x = f2bf(O[dt][0] * inv);
        o.y = f2bf(O[dt][1] * inv);
        o.z = f2bf(O[dt][2] * inv);
        o.w = f2bf(O[dt][3] * inv);
        *(ushort4*)(attn_bf + (size_t)(qr0 + l16) * D_MODEL + h * 64 + dt * 16 + quad * 4) = o;
    }
}

extern "C" void kernel_launch(void* const* d_in, const int* in_sizes, int n_in,
                              void* d_out, int out_size, void* d_ws, size_t ws_size,
                              hipStream_t stream) {
    const float* x     = (const float*)d_in[0];
    const float* w_qkv = (const float*)d_in[1];
    const float* w_out = (const float*)d_in[2];
    const float* ln_g  = (const float*)d_in[3];
    const float* ln_b  = (const float*)d_in[4];

    float* out   = (float*)d_out;                       // [4096,1024]
    float* out_k = (float*)d_out + 4194304;             // [16,4096,64]
    float* out_v = (float*)d_out + 8388608;             // [16,4096,64]

    char* ws = (char*)d_ws;
    const size_t MiB = 1048576;
    float*          qkv_f   = (float*)(ws);                    // [4096,3072] fp32   @0..48MiB
    unsigned short* h_bf    = (unsigned short*)(ws + 48*MiB);  // [4096,1024] bf16   @48..56 (dead after gemm1)
    unsigned short* wqkvT   = (unsigned short*)(ws + 56*MiB);  // [3072,1024] bf16   @56..62 (dead after gemm1)
    unsigned short* q_bf    = (unsigned short*)(ws + 48*MiB);  // [16,4096,64] bf16  @48..56 (after gemm1)
    unsigned short* k_bf    = (unsigned short*)(ws + 56*MiB);  // [16,4096,64] bf16  @56..64
    unsigned short* vt_bf   = (unsigned short*)(ws + 64*MiB);  // [16,64,4096] bf16  @64..72
    unsigned short* attn_bf = (unsigned short*)(ws);           // [4096,1024] bf16   @0..8 (after rope)
    unsigned short* woutT   = (unsigned short*)(ws + 72*MiB);  // [1024,1024] bf16   @72..74

    transpose_cvt<<<dim3(16, 48), 256, 0, stream>>>(w_qkv, wqkvT, D_MODEL, QKV_COLS);
    transpose_cvt<<<dim3(16, 16), 256, 0, stream>>>(w_out, woutT, D_MODEL, D_MODEL);
    ln_kernel<<<N_SEQ, 256, 0, stream>>>(x, ln_g, ln_b, h_bf);
    gemm_bt128<<<dim3(32, 24), 256, 0, stream>>>(h_bf, wqkvT, qkv_f, N_SEQ, QKV_COLS, D_MODEL);
    rope_cache_kernel<<<N_SEQ, 256, 0, stream>>>(qkv_f, out_k, out_v, q_bf, k_bf, vt_bf);
    flash_mfma<<<dim3(64, 16), 256, 0, stream>>>(q_bf, k_bf, vt_bf, attn_bf);
    gemm_bt128<<<dim3(32, 8), 256, 0, stream>>>(attn_bf, woutT, out, N_SEQ, D_MODEL, D_MODEL);
}

// Round 4
// 319.968 us; speedup vs baseline: 10.9621x; 1.0666x over previous
//
#include <hip/hip_runtime.h>
#include <math.h>

#define D_MODEL 1024
#define N_SEQ   4096
#define N_HEADS 16
#define DHEAD   64
#define QKV_COLS 3072   // 3 * 1024

typedef short bf16x8 __attribute__((ext_vector_type(8)));
typedef float f32x4  __attribute__((ext_vector_type(4)));

static __device__ __forceinline__ unsigned short f2bf(float f) {
    union { float f; unsigned u; } v; v.f = f;
    unsigned r = (v.u + 0x7fffu + ((v.u >> 16) & 1u)) >> 16;
    return (unsigned short)r;
}

typedef __attribute__((address_space(1))) const void* gas_t;
typedef __attribute__((address_space(3))) void* las_t;
static __device__ __forceinline__ void load_lds16(const unsigned short* g, unsigned short* l) {
    __builtin_amdgcn_global_load_lds((gas_t)g, (las_t)l, 16, 0, 0);
}

// ---------------- LayerNorm: one block per row, bf16 out ----------------
__global__ __launch_bounds__(256) void ln_kernel(const float* __restrict__ x,
                                                 const float* __restrict__ g,
                                                 const float* __restrict__ b,
                                                 unsigned short* __restrict__ h) {
    int row = blockIdx.x;
    int t = threadIdx.x;
    float4 v = ((const float4*)(x + (size_t)row * D_MODEL))[t];
    float s  = v.x + v.y + v.z + v.w;
    float ss = v.x*v.x + v.y*v.y + v.z*v.z + v.w*v.w;
    for (int off = 32; off; off >>= 1) {
        s  += __shfl_down(s, off);
        ss += __shfl_down(ss, off);
    }
    __shared__ float sm[4], ssm[4];
    __shared__ float mu_s, rs_s;
    int wave = t >> 6, lane = t & 63;
    if (lane == 0) { sm[wave] = s; ssm[wave] = ss; }
    __syncthreads();
    if (t == 0) {
        float S = 0.f, SS = 0.f;
        for (int w = 0; w < 4; w++) { S += sm[w]; SS += ssm[w]; }
        float mu = S / D_MODEL;
        float var = SS / D_MODEL - mu * mu;
        mu_s = mu;
        rs_s = rsqrtf(var + 1e-5f);
    }
    __syncthreads();
    float mu = mu_s, rs = rs_s;
    float4 gv = ((const float4*)g)[t];
    float4 bv = ((const float4*)b)[t];
    ushort4 o;
    o.x = f2bf((v.x - mu) * rs * gv.x + bv.x);
    o.y = f2bf((v.y - mu) * rs * gv.y + bv.y);
    o.z = f2bf((v.z - mu) * rs * gv.z + bv.z);
    o.w = f2bf((v.w - mu) * rs * gv.w + bv.w);
    *(ushort4*)(h + (size_t)row * D_MODEL + t * 4) = o;
}

// ------------- transpose + fp32->bf16: W[K][N] -> Wt[N][K] -------------
__global__ __launch_bounds__(256) void transpose_cvt(const float* __restrict__ W,
                                                     unsigned short* __restrict__ Wt,
                                                     int K, int N) {
    __shared__ float tile[64][65];
    int k0 = blockIdx.x * 64, n0 = blockIdx.y * 64;
    int t = threadIdx.x;
#pragma unroll
    for (int p = 0; p < 16; p++) {
        int idx = p * 256 + t;
        int r = idx >> 6, c = idx & 63;
        tile[r][c] = W[(size_t)(k0 + r) * N + n0 + c];
    }
    __syncthreads();
#pragma unroll
    for (int p = 0; p < 16; p++) {
        int idx = p * 256 + t;
        int r2 = idx >> 6, c2 = idx & 63;
        Wt[(size_t)(n0 + r2) * K + k0 + c2] = f2bf(tile[c2][r2]);
    }
}

// ---- m97-style MFMA bf16 GEMM: C[M,N] = A[M,K] * Bt[N,K]^T, fp32 out ----
__global__ __launch_bounds__(256) void gemm_bt128(const unsigned short* __restrict__ A,
                                                  const unsigned short* __restrict__ Bt,
                                                  float* __restrict__ C,
                                                  int M, int N, int K) {
    __shared__ unsigned short As[128 * 32];
    __shared__ unsigned short Bs[128 * 32];
    int t = threadIdx.x;
    int w = t >> 6, lane = t & 63;
    int l16 = lane & 15, quad = lane >> 4;
    int wr = w >> 1, wc = w & 1;
    int m0 = blockIdx.x * 128, n0 = blockIdx.y * 128;
    int srow = lane >> 2, scol = (lane & 3) * 8;
    int c0 = w * 2, c1 = c0 + 1;

    f32x4 acc[4][4] = {};

    for (int k0 = 0; k0 < K; k0 += 32) {
        __syncthreads();
        load_lds16(A  + (size_t)(m0 + c0 * 16 + srow) * K + k0 + scol, &As[c0 * 512 + lane * 8]);
        load_lds16(A  + (size_t)(m0 + c1 * 16 + srow) * K + k0 + scol, &As[c1 * 512 + lane * 8]);
        load_lds16(Bt + (size_t)(n0 + c0 * 16 + srow) * K + k0 + scol, &Bs[c0 * 512 + lane * 8]);
        load_lds16(Bt + (size_t)(n0 + c1 * 16 + srow) * K + k0 + scol, &Bs[c1 * 512 + lane * 8]);
        __syncthreads();
        bf16x8 a[4], b[4];
#pragma unroll
        for (int mt = 0; mt < 4; mt++)
            a[mt] = *(const bf16x8*)&As[(wr * 64 + mt * 16 + l16) * 32 + quad * 8];
#pragma unroll
        for (int nt = 0; nt < 4; nt++)
            b[nt] = *(const bf16x8*)&Bs[(wc * 64 + nt * 16 + l16) * 32 + quad * 8];
#pragma unroll
        for (int mt = 0; mt < 4; mt++)
#pragma unroll
            for (int nt = 0; nt < 4; nt++)
                acc[mt][nt] = __builtin_amdgcn_mfma_f32_16x16x32_bf16(a[mt], b[nt], acc[mt][nt], 0, 0, 0);
    }
#pragma unroll
    for (int mt = 0; mt < 4; mt++)
#pragma unroll
        for (int nt = 0; nt < 4; nt++)
#pragma unroll
            for (int r = 0; r < 4; r++)
                C[(size_t)(m0 + wr * 64 + mt * 16 + quad * 4 + r) * N + n0 + wc * 64 + nt * 16 + l16] =
                    acc[mt][nt][r];
}

// --------- rope + caches. grid (64 ntiles, 16 heads), 256 thr ----------
// Reads the head's q/k/v 64x64 fp32 sub-blocks, writes fp32 caches (coalesced),
// bf16 roped q/k [h][n][d], and bf16 v^T [h][d][n] via LDS transpose.
__global__ __launch_bounds__(256) void rope_cache_kernel(const float* __restrict__ qkv,
                                                         float* __restrict__ out_k,
                                                         float* __restrict__ out_v,
                                                         unsigned short* __restrict__ q_bf,
                                                         unsigned short* __restrict__ k_bf,
                                                         unsigned short* __restrict__ vt_bf) {
    __shared__ unsigned short Vt[64 * 72];   // row-major [n][d+pad]
    int nt = blockIdx.x, h = blockIdx.y;
    int n0 = nt * 64;
    int t = threadIdx.x;
    int row = t >> 2;              // n-local
    int n = n0 + row;
    const float* src = qkv + (size_t)n * QKV_COLS + h * 64;
    size_t nd_base = ((size_t)h * N_SEQ + n) * 64;
#pragma unroll
    for (int j = 0; j < 4; j++) {
        int c = (t & 3) * 4 + j * 16;      // d-local, multiple of 4
        float4 q4 = *(const float4*)(src + c);
        float4 k4 = *(const float4*)(src + 1024 + c);
        float4 v4 = *(const float4*)(src + 2048 + c);
        *(float4*)(out_k + nd_base + c) = k4;
        *(float4*)(out_v + nd_base + c) = v4;
        float i0 = (float)(c >> 1), i1 = i0 + 1.f;
        float if0 = powf(10000.0f, -i0 / 32.0f);
        float if1 = powf(10000.0f, -i1 / 32.0f);
        float s0, c0s, s1, c1s;
        sincosf((float)n * if0, &s0, &c0s);
        sincosf((float)n * if1, &s1, &c1s);
        ushort4 qo, ko;
        qo.x = f2bf(q4.x * c0s - q4.y * s0); qo.y = f2bf(q4.y * c0s + q4.x * s0);
        qo.z = f2bf(q4.z * c1s - q4.w * s1); qo.w = f2bf(q4.w * c1s + q4.z * s1);
        ko.x = f2bf(k4.x * c0s - k4.y * s0); ko.y = f2bf(k4.y * c0s + k4.x * s0);
        ko.z = f2bf(k4.z * c1s - k4.w * s1); ko.w = f2bf(k4.w * c1s + k4.z * s1);
        *(ushort4*)(q_bf + nd_base + c) = qo;
        *(ushort4*)(k_bf + nd_base + c) = ko;
        ushort4 vo;
        vo.x = f2bf(v4.x); vo.y = f2bf(v4.y); vo.z = f2bf(v4.z); vo.w = f2bf(v4.w);
        *(ushort4*)&Vt[row * 72 + c] = vo;
    }
    __syncthreads();
    // transpose out: thread t -> d = t>>2, n-block (t&3)*16
    int d = t >> 2;
    int nb = (t & 3) * 16;
    unsigned short tmp[16];
#pragma unroll
    for (int i = 0; i < 16; i++) tmp[i] = Vt[(nb + i) * 72 + d];
    unsigned short* dst = vt_bf + ((size_t)h * DHEAD + d) * N_SEQ + n0 + nb;
#pragma unroll
    for (int i = 0; i < 16; i++) dst[i] = tmp[i];
}

// ---------------- MFMA flash attention (causal, S^T form) ----------------
// 512 blocks x 256 thr. Block = 128 queries x 1 head; wave w owns 32 queries.
// K/V tiles: unpadded 64x64, XOR-swizzled 16B blocks, staged via global_load_lds.
__global__ __launch_bounds__(256) void flash_mfma(const unsigned short* __restrict__ q_bf,
                                                  const unsigned short* __restrict__ k_bf,
                                                  const unsigned short* __restrict__ vt_bf,
                                                  unsigned short* __restrict__ attn_bf) {
    int idx = blockIdx.x;
    int h  = ((idx & 7) << 1) | (idx >> 8);      // 2 heads per XCD class
    int Qt = 31 - ((idx >> 3) & 31);             // heavy tiles first
    int t  = threadIdx.x;
    int w  = t >> 6, lane = t & 63;
    int l16 = lane & 15, quad = lane >> 4;

    __shared__ unsigned short Ks[64 * 64];
    __shared__ unsigned short Vs[64 * 64];
    __shared__ unsigned short Ps[4 * 32 * 72];
    unsigned short* pw = &Ps[w * 32 * 72];

    int qr0 = Qt * 128 + w * 32;
    const unsigned short* Kg = k_bf + (size_t)h * N_SEQ * DHEAD;
    const unsigned short* Vg = vt_bf + (size_t)h * DHEAD * N_SEQ;

    // Q B-frags (from global, rows q, contiguous)
    bf16x8 bq[2][2];
#pragma unroll
    for (int qg = 0; qg < 2; qg++) {
        const unsigned short* qp = q_bf + ((size_t)h * N_SEQ + qr0 + qg * 16 + l16) * 64 + quad * 8;
        bq[qg][0] = *(const bf16x8*)(qp);
        bq[qg][1] = *(const bf16x8*)(qp + 32);
    }
    f32x4 O[2][4] = {};
    float lp[2] = {0.f, 0.f};

    int my_kmax = (qr0 + 31) >> 6;   // inclusive
    int kt_end  = 2 * Qt + 1;        // inclusive (block)

    int srow = t >> 3;               // 0..31
    int scol = ((t & 7) ^ (srow & 7)) * 8;   // swizzled source column (shorts)

    for (int kt = 0; kt <= kt_end; kt++) {
        int k0 = kt << 6;
        __syncthreads();
        load_lds16(Kg + (size_t)(k0 + srow) * 64 + scol,        &Ks[t * 8]);
        load_lds16(Kg + (size_t)(k0 + srow + 32) * 64 + scol,   &Ks[t * 8 + 2048]);
        load_lds16(Vg + (size_t)srow * N_SEQ + k0 + scol,       &Vs[t * 8]);
        load_lds16(Vg + (size_t)(srow + 32) * N_SEQ + k0 + scol, &Vs[t * 8 + 2048]);
        __syncthreads();
        if (kt > my_kmax) continue;

        // ---- S^T = K * Q^T, exp, P to LDS ----
#pragma unroll
        for (int tt = 0; tt < 4; tt++) {
            int kbase = k0 + tt * 16;
            if (kbase <= qr0 + 31) {
                int krow = tt * 16 + l16;
                int sw8 = krow & 7;
                bf16x8 kf0 = *(const bf16x8*)&Ks[krow * 64 + ((quad ^ sw8) * 8)];
                bf16x8 kf1 = *(const bf16x8*)&Ks[krow * 64 + (((quad + 4) ^ sw8) * 8)];
#pragma unroll
                for (int qg = 0; qg < 2; qg++) {
                    int qbase = qr0 + qg * 16;
                    ushort4 pk = {0, 0, 0, 0};
                    if (kbase <= qbase + 15) {
                        f32x4 s = (f32x4){0.f, 0.f, 0.f, 0.f};
                        s = __builtin_amdgcn_mfma_f32_16x16x32_bf16(kf0, bq[qg][0], s, 0, 0, 0);
                        s = __builtin_amdgcn_mfma_f32_16x16x32_bf16(kf1, bq[qg][1], s, 0, 0, 0);
                        unsigned short pr[4];
#pragma unroll
                        for (int r = 0; r < 4; r++) {
                            float p = __expf(s[r] * 0.125f);
                            int key = kbase + quad * 4 + r;
                            if (key > qbase + l16) p = 0.f;
                            lp[qg] += p;
                            pr[r] = f2bf(p);
                        }
                        pk.x = pr[0]; pk.y = pr[1]; pk.z = pr[2]; pk.w = pr[3];
                    }
                    *(ushort4*)&pw[(qg * 16 + l16) * 72 + tt * 16 + quad * 4] = pk;
                }
            } else {
                ushort4 z = {0, 0, 0, 0};
#pragma unroll
                for (int qg = 0; qg < 2; qg++)
                    *(ushort4*)&pw[(qg * 16 + l16) * 72 + tt * 16 + quad * 4] = z;
            }
        }
        // ---- O^T += V^T * P^T ----
#pragma unroll
        for (int c = 0; c < 2; c++) {
            bf16x8 pb0 = *(const bf16x8*)&pw[(l16) * 72 + c * 32 + quad * 8];
            bf16x8 pb1 = *(const bf16x8*)&pw[(16 + l16) * 72 + c * 32 + quad * 8];
#pragma unroll
            for (int dt = 0; dt < 4; dt++) {
                int vrow = dt * 16 + l16;
                bf16x8 va = *(const bf16x8*)&Vs[vrow * 64 + (((quad + 4 * c) ^ (vrow & 7)) * 8)];
                O[0][dt] = __builtin_amdgcn_mfma_f32_16x16x32_bf16(va, pb0, O[0][dt], 0, 0, 0);
                O[1][dt] = __builtin_amdgcn_mfma_f32_16x16x32_bf16(va, pb1, O[1][dt], 0, 0, 0);
            }
        }
    }
#pragma unroll
    for (int qg = 0; qg < 2; qg++) {
        float l = lp[qg];
        l += __shfl_xor(l, 16);
        l += __shfl_xor(l, 32);
        float inv = 1.0f / l;
#pragma unroll
        for (int dt = 0; dt < 4; dt++) {
            ushort4 o;
            o.x = f2bf(O[qg][dt][0] * inv);
            o.y = f2bf(O[qg][dt][1] * inv);
            o.z = f2bf(O[qg][dt][2] * inv);
            o.w = f2bf(O[qg][dt][3] * inv);
            *(ushort4*)(attn_bf + (size_t)(qr0 + qg * 16 + l16) * D_MODEL + h * 64 + dt * 16 + quad * 4) = o;
        }
    }
}

extern "C" void kernel_launch(void* const* d_in, const int* in_sizes, int n_in,
                              void* d_out, int out_size, void* d_ws, size_t ws_size,
                              hipStream_t stream) {
    const float* x     = (const float*)d_in[0];
    const float* w_qkv = (const float*)d_in[1];
    const float* w_out = (const float*)d_in[2];
    const float* ln_g  = (const float*)d_in[3];
    const float* ln_b  = (const float*)d_in[4];

    float* out   = (float*)d_out;                       // [4096,1024]
    float* out_k = (float*)d_out + 4194304;             // [16,4096,64]
    float* out_v = (float*)d_out + 8388608;             // [16,4096,64]

    char* ws = (char*)d_ws;
    const size_t MiB = 1048576;
    float*          qkv_f   = (float*)(ws);                    // [4096,3072] fp32   @0..48
    unsigned short* h_bf    = (unsigned short*)(ws + 48*MiB);  // [4096,1024] bf16   @48..56 (dead after gemm1)
    unsigned short* wqkvT   = (unsigned short*)(ws + 56*MiB);  // [3072,1024] bf16   @56..62 (dead after gemm1)
    unsigned short* q_bf    = (unsigned short*)(ws + 48*MiB);  // [16,4096,64] bf16  @48..56
    unsigned short* k_bf    = (unsigned short*)(ws + 56*MiB);  // [16,4096,64] bf16  @56..64
    unsigned short* vt_bf   = (unsigned short*)(ws + 64*MiB);  // [16,64,4096] bf16  @64..72
    unsigned short* attn_bf = (unsigned short*)(ws);           // [4096,1024] bf16   @0..8 (qkv_f dead)
    unsigned short* woutT   = (unsigned short*)(ws + 72*MiB);  // [1024,1024] bf16   @72..74

    transpose_cvt<<<dim3(16, 48), 256, 0, stream>>>(w_qkv, wqkvT, D_MODEL, QKV_COLS);
    transpose_cvt<<<dim3(16, 16), 256, 0, stream>>>(w_out, woutT, D_MODEL, D_MODEL);
    ln_kernel<<<N_SEQ, 256, 0, stream>>>(x, ln_g, ln_b, h_bf);
    gemm_bt128<<<dim3(32, 24), 256, 0, stream>>>(h_bf, wqkvT, qkv_f, N_SEQ, QKV_COLS, D_MODEL);
    rope_cache_kernel<<<dim3(64, 16), 256, 0, stream>>>(qkv_f, out_k, out_v, q_bf, k_bf, vt_bf);
    flash_mfma<<<512, 256, 0, stream>>>(q_bf, k_bf, vt_bf, attn_bf);
    gemm_bt128<<<dim3(32, 8), 256, 0, stream>>>(attn_bf, woutT, out, N_SEQ, D_MODEL, D_MODEL);
}

// Round 6
// 273.975 us; speedup vs baseline: 12.8024x; 1.1679x over previous
//
#include <hip/hip_runtime.h>
#include <math.h>

#define D_MODEL 1024
#define N_SEQ   4096
#define N_HEADS 16
#define DHEAD   64
#define QKV_COLS 3072   // 3 * 1024

typedef short bf16x8 __attribute__((ext_vector_type(8)));
typedef short bf16x4 __attribute__((ext_vector_type(4)));
typedef float f32x4  __attribute__((ext_vector_type(4)));

#define MFMA32(a, b, c) __builtin_amdgcn_mfma_f32_16x16x32_bf16(a, b, c, 0, 0, 0)
// v_mfma_f32_16x16x16_bf16 (2/2/4 regs) — gfx90a-lineage builtin, valid on gfx950.
#define MFMA16(a, b, c) __builtin_amdgcn_mfma_f32_16x16x16bf16_1k(a, b, c, 0, 0, 0)

static __device__ __forceinline__ unsigned short f2bf(float f) {
    union { float f; unsigned u; } v; v.f = f;
    unsigned r = (v.u + 0x7fffu + ((v.u >> 16) & 1u)) >> 16;
    return (unsigned short)r;
}

// pack 4 floats -> 4 bf16 by truncation (1 v_perm_b32 per pair)
static __device__ __forceinline__ bf16x4 pack_bf16x4(float a, float b, float c, float d) {
    union { float f; unsigned u; } x0, x1, x2, x3;
    x0.f = a; x1.f = b; x2.f = c; x3.f = d;
    union { unsigned u[2]; bf16x4 v; } r;
    r.u[0] = __builtin_amdgcn_perm(x1.u, x0.u, 0x07060302u);
    r.u[1] = __builtin_amdgcn_perm(x3.u, x2.u, 0x07060302u);
    return r.v;
}

typedef __attribute__((address_space(1))) const void* gas_t;
typedef __attribute__((address_space(3))) void* las_t;
static __device__ __forceinline__ void load_lds16(const unsigned short* g, unsigned short* l) {
    __builtin_amdgcn_global_load_lds((gas_t)g, (las_t)l, 16, 0, 0);
}

// ---------------- LayerNorm: one block per row, bf16 out ----------------
__global__ __launch_bounds__(256) void ln_kernel(const float* __restrict__ x,
                                                 const float* __restrict__ g,
                                                 const float* __restrict__ b,
                                                 unsigned short* __restrict__ h) {
    int row = blockIdx.x;
    int t = threadIdx.x;
    float4 v = ((const float4*)(x + (size_t)row * D_MODEL))[t];
    float s  = v.x + v.y + v.z + v.w;
    float ss = v.x*v.x + v.y*v.y + v.z*v.z + v.w*v.w;
    for (int off = 32; off; off >>= 1) {
        s  += __shfl_down(s, off);
        ss += __shfl_down(ss, off);
    }
    __shared__ float sm[4], ssm[4];
    __shared__ float mu_s, rs_s;
    int wave = t >> 6, lane = t & 63;
    if (lane == 0) { sm[wave] = s; ssm[wave] = ss; }
    __syncthreads();
    if (t == 0) {
        float S = 0.f, SS = 0.f;
        for (int w = 0; w < 4; w++) { S += sm[w]; SS += ssm[w]; }
        float mu = S / D_MODEL;
        float var = SS / D_MODEL - mu * mu;
        mu_s = mu;
        rs_s = rsqrtf(var + 1e-5f);
    }
    __syncthreads();
    float mu = mu_s, rs = rs_s;
    float4 gv = ((const float4*)g)[t];
    float4 bv = ((const float4*)b)[t];
    ushort4 o;
    o.x = f2bf((v.x - mu) * rs * gv.x + bv.x);
    o.y = f2bf((v.y - mu) * rs * gv.y + bv.y);
    o.z = f2bf((v.z - mu) * rs * gv.z + bv.z);
    o.w = f2bf((v.w - mu) * rs * gv.w + bv.w);
    *(ushort4*)(h + (size_t)row * D_MODEL + t * 4) = o;
}

// ------------- transpose + fp32->bf16: W[K][N] -> Wt[N][K] -------------
__global__ __launch_bounds__(256) void transpose_cvt(const float* __restrict__ W,
                                                     unsigned short* __restrict__ Wt,
                                                     int K, int N) {
    __shared__ float tile[64][65];
    int k0 = blockIdx.x * 64, n0 = blockIdx.y * 64;
    int t = threadIdx.x;
#pragma unroll
    for (int p = 0; p < 16; p++) {
        int idx = p * 256 + t;
        int r = idx >> 6, c = idx & 63;
        tile[r][c] = W[(size_t)(k0 + r) * N + n0 + c];
    }
    __syncthreads();
#pragma unroll
    for (int p = 0; p < 16; p++) {
        int idx = p * 256 + t;
        int r2 = idx >> 6, c2 = idx & 63;
        Wt[(size_t)(n0 + r2) * K + k0 + c2] = f2bf(tile[c2][r2]);
    }
}

// ---- m97-style MFMA bf16 GEMM: C[M,N] = A[M,K] * Bt[N,K]^T, fp32 out ----
__global__ __launch_bounds__(256) void gemm_bt128(const unsigned short* __restrict__ A,
                                                  const unsigned short* __restrict__ Bt,
                                                  float* __restrict__ C,
                                                  int M, int N, int K) {
    __shared__ unsigned short As[128 * 32];
    __shared__ unsigned short Bs[128 * 32];
    int t = threadIdx.x;
    int w = t >> 6, lane = t & 63;
    int l16 = lane & 15, quad = lane >> 4;
    int wr = w >> 1, wc = w & 1;
    int m0 = blockIdx.x * 128, n0 = blockIdx.y * 128;
    int srow = lane >> 2, scol = (lane & 3) * 8;
    int c0 = w * 2, c1 = c0 + 1;

    f32x4 acc[4][4] = {};

    for (int k0 = 0; k0 < K; k0 += 32) {
        __syncthreads();
        load_lds16(A  + (size_t)(m0 + c0 * 16 + srow) * K + k0 + scol, &As[c0 * 512 + lane * 8]);
        load_lds16(A  + (size_t)(m0 + c1 * 16 + srow) * K + k0 + scol, &As[c1 * 512 + lane * 8]);
        load_lds16(Bt + (size_t)(n0 + c0 * 16 + srow) * K + k0 + scol, &Bs[c0 * 512 + lane * 8]);
        load_lds16(Bt + (size_t)(n0 + c1 * 16 + srow) * K + k0 + scol, &Bs[c1 * 512 + lane * 8]);
        __syncthreads();
        bf16x8 a[4], b[4];
#pragma unroll
        for (int mt = 0; mt < 4; mt++)
            a[mt] = *(const bf16x8*)&As[(wr * 64 + mt * 16 + l16) * 32 + quad * 8];
#pragma unroll
        for (int nt = 0; nt < 4; nt++)
            b[nt] = *(const bf16x8*)&Bs[(wc * 64 + nt * 16 + l16) * 32 + quad * 8];
#pragma unroll
        for (int mt = 0; mt < 4; mt++)
#pragma unroll
            for (int nt = 0; nt < 4; nt++)
                acc[mt][nt] = MFMA32(a[mt], b[nt], acc[mt][nt]);
    }
#pragma unroll
    for (int mt = 0; mt < 4; mt++)
#pragma unroll
        for (int nt = 0; nt < 4; nt++)
#pragma unroll
            for (int r = 0; r < 4; r++)
                C[(size_t)(m0 + wr * 64 + mt * 16 + quad * 4 + r) * N + n0 + wc * 64 + nt * 16 + l16] =
                    acc[mt][nt][r];
}

// --------- rope + caches. grid (64 ntiles, 16 heads), 256 thr ----------
__global__ __launch_bounds__(256) void rope_cache_kernel(const float* __restrict__ qkv,
                                                         float* __restrict__ out_k,
                                                         float* __restrict__ out_v,
                                                         unsigned short* __restrict__ q_bf,
                                                         unsigned short* __restrict__ k_bf,
                                                         unsigned short* __restrict__ vt_bf) {
    __shared__ unsigned short Vt[64 * 72];
    int nt = blockIdx.x, h = blockIdx.y;
    int n0 = nt * 64;
    int t = threadIdx.x;
    int row = t >> 2;
    int n = n0 + row;
    const float* src = qkv + (size_t)n * QKV_COLS + h * 64;
    size_t nd_base = ((size_t)h * N_SEQ + n) * 64;
#pragma unroll
    for (int j = 0; j < 4; j++) {
        int c = (t & 3) * 4 + j * 16;
        float4 q4 = *(const float4*)(src + c);
        float4 k4 = *(const float4*)(src + 1024 + c);
        float4 v4 = *(const float4*)(src + 2048 + c);
        *(float4*)(out_k + nd_base + c) = k4;
        *(float4*)(out_v + nd_base + c) = v4;
        float i0 = (float)(c >> 1), i1 = i0 + 1.f;
        float if0 = powf(10000.0f, -i0 / 32.0f);
        float if1 = powf(10000.0f, -i1 / 32.0f);
        float s0, c0s, s1, c1s;
        sincosf((float)n * if0, &s0, &c0s);
        sincosf((float)n * if1, &s1, &c1s);
        ushort4 qo, ko;
        qo.x = f2bf(q4.x * c0s - q4.y * s0); qo.y = f2bf(q4.y * c0s + q4.x * s0);
        qo.z = f2bf(q4.z * c1s - q4.w * s1); qo.w = f2bf(q4.w * c1s + q4.z * s1);
        ko.x = f2bf(k4.x * c0s - k4.y * s0); ko.y = f2bf(k4.y * c0s + k4.x * s0);
        ko.z = f2bf(k4.z * c1s - k4.w * s1); ko.w = f2bf(k4.w * c1s + k4.z * s1);
        *(ushort4*)(q_bf + nd_base + c) = qo;
        *(ushort4*)(k_bf + nd_base + c) = ko;
        ushort4 vo;
        vo.x = f2bf(v4.x); vo.y = f2bf(v4.y); vo.z = f2bf(v4.z); vo.w = f2bf(v4.w);
        *(ushort4*)&Vt[row * 72 + c] = vo;
    }
    __syncthreads();
    int d = t >> 2;
    int nb = (t & 3) * 16;
    unsigned short tmp[16];
#pragma unroll
    for (int i = 0; i < 16; i++) tmp[i] = Vt[(nb + i) * 72 + d];
    unsigned short* dst = vt_bf + ((size_t)h * DHEAD + d) * N_SEQ + n0 + nb;
#pragma unroll
    for (int i = 0; i < 16; i++) dst[i] = tmp[i];
}

// ------------- MFMA flash attention (causal, S^T form, split-K) -------------
// 1280 blocks x 256 thr. Unit u<72: partial chunk (Qt>=8, 16-ktile chunk c),
// writes fp32 O^T partial + l. Unit u>=72: Qt<8, full range, writes attn directly.
// PV uses 16x16x16 mfma with P kept in registers (C-layout == B-operand).
__global__ __launch_bounds__(256, 4) void flash_mfma(const unsigned short* __restrict__ q_bf,
                                                     const unsigned short* __restrict__ k_bf,
                                                     const unsigned short* __restrict__ vt_bf,
                                                     unsigned short* __restrict__ attn_bf,
                                                     float* __restrict__ part_O,
                                                     float* __restrict__ part_l) {
    int idx = blockIdx.x;
    int h = idx & 15;                  // heads in low bits -> spread over XCDs
    int u = idx >> 4;                  // 0..79, heavy-first
    int Qt, cc;
    bool partial = (u < 72);
    if (partial) {
        int r = 71 - u;
        if (r < 16)      { Qt = 8 + (r >> 1); cc = r & 1; }
        else if (r < 40) { int q3 = r - 16; int d3 = q3 / 3; Qt = 16 + d3; cc = q3 - 3 * d3; }
        else             { int q4 = r - 40; Qt = 24 + (q4 >> 2); cc = q4 & 3; }
    } else { Qt = 79 - u; cc = 0; }
    int kt0 = cc * 16;
    int kt_end = min(kt0 + 15, 2 * Qt + 1);

    int t = threadIdx.x;
    int w = t >> 6, lane = t & 63;
    int l16 = lane & 15, quad = lane >> 4;
    int sw = l16 & 7;

    __shared__ unsigned short Ks[64 * 64];
    __shared__ unsigned short Vs[64 * 64];

    int qr0 = Qt * 128 + w * 32;
    const unsigned short* Kg = k_bf + (size_t)h * N_SEQ * DHEAD;
    const unsigned short* Vg = vt_bf + (size_t)h * DHEAD * N_SEQ;

    bf16x8 bq[2][2];
#pragma unroll
    for (int qg = 0; qg < 2; qg++) {
        const unsigned short* qp = q_bf + ((size_t)h * N_SEQ + qr0 + qg * 16 + l16) * 64 + quad * 8;
        bq[qg][0] = *(const bf16x8*)(qp);
        bq[qg][1] = *(const bf16x8*)(qp + 32);
    }
    f32x4 O[2][4] = {};
    float lp[2] = {0.f, 0.f};
    int my_kmax = (qr0 + 31) >> 6;

    int srow = t >> 3;
    int scol = ((t & 7) ^ (srow & 7)) * 8;
    const float CEXP = 0.18033688011112042f;   // 0.125 * log2(e)

    for (int kt = kt0; kt <= kt_end; kt++) {
        int k0 = kt << 6;
        __syncthreads();
        load_lds16(Kg + (size_t)(k0 + srow) * 64 + scol,         &Ks[t * 8]);
        load_lds16(Kg + (size_t)(k0 + srow + 32) * 64 + scol,    &Ks[t * 8 + 2048]);
        load_lds16(Vg + (size_t)srow * N_SEQ + k0 + scol,        &Vs[t * 8]);
        load_lds16(Vg + (size_t)(srow + 32) * N_SEQ + k0 + scol, &Vs[t * 8 + 2048]);
        __syncthreads();
        if (kt > my_kmax) continue;

        bf16x4 pf[2][4];
#pragma unroll
        for (int tt = 0; tt < 4; tt++) {
            int kbase = k0 + tt * 16;
            bf16x4 pz = (bf16x4){0, 0, 0, 0};
            if (kbase >= qr0 + 32) { pf[0][tt] = pz; pf[1][tt] = pz; continue; }
            int krow = tt * 16 + l16;
            bf16x8 kf0 = *(const bf16x8*)&Ks[krow * 64 + ((quad ^ sw) * 8)];
            bf16x8 kf1 = *(const bf16x8*)&Ks[krow * 64 + (((quad + 4) ^ sw) * 8)];
#pragma unroll
            for (int qg = 0; qg < 2; qg++) {
                int qb = qr0 + qg * 16;
                if (kbase > qb) { pf[qg][tt] = pz; continue; }
                f32x4 s = (f32x4){0.f, 0.f, 0.f, 0.f};
                s = MFMA32(kf0, bq[qg][0], s);
                s = MFMA32(kf1, bq[qg][1], s);
                float p0 = exp2f(s[0] * CEXP);
                float p1 = exp2f(s[1] * CEXP);
                float p2 = exp2f(s[2] * CEXP);
                float p3 = exp2f(s[3] * CEXP);
                if (kbase == qb) {   // diagonal tile: mask key > q (lane-static compare)
                    if (quad * 4 + 0 > l16) p0 = 0.f;
                    if (quad * 4 + 1 > l16) p1 = 0.f;
                    if (quad * 4 + 2 > l16) p2 = 0.f;
                    if (quad * 4 + 3 > l16) p3 = 0.f;
                }
                lp[qg] += (p0 + p1) + (p2 + p3);
                pf[qg][tt] = pack_bf16x4(p0, p1, p2, p3);
            }
        }
        // O^T += V^T * P^T, 16-key chunks, P from registers
#pragma unroll
        for (int tt = 0; tt < 4; tt++) {
            if (k0 + tt * 16 < qr0 + 32) {
#pragma unroll
                for (int dt = 0; dt < 4; dt++) {
                    int vrow = dt * 16 + l16;
                    bf16x4 va = *(const bf16x4*)&Vs[vrow * 64 +
                                (((2 * tt + (quad >> 1)) ^ sw) * 8) + (quad & 1) * 4];
                    O[0][dt] = MFMA16(va, pf[0][tt], O[0][dt]);
                    O[1][dt] = MFMA16(va, pf[1][tt], O[1][dt]);
                }
            }
        }
    }

#pragma unroll
    for (int qg = 0; qg < 2; qg++) {
        float l = lp[qg];
        l += __shfl_xor(l, 16);
        l += __shfl_xor(l, 32);
        if (!partial) {
            float inv = 1.0f / l;
#pragma unroll
            for (int dt = 0; dt < 4; dt++) {
                ushort4 o;
                o.x = f2bf(O[qg][dt][0] * inv);
                o.y = f2bf(O[qg][dt][1] * inv);
                o.z = f2bf(O[qg][dt][2] * inv);
                o.w = f2bf(O[qg][dt][3] * inv);
                *(ushort4*)(attn_bf + (size_t)(qr0 + qg * 16 + l16) * D_MODEL + h * 64 + dt * 16 + quad * 4) = o;
            }
        } else {
            int uid = h * 72 + u;
            size_t ob = (size_t)uid * 8192;
            int qcol = w * 32 + qg * 16 + l16;
#pragma unroll
            for (int dt = 0; dt < 4; dt++)
#pragma unroll
                for (int r = 0; r < 4; r++)
                    part_O[ob + (size_t)(dt * 16 + quad * 4 + r) * 128 + qcol] = O[qg][dt][r];
            if (quad == 0) part_l[uid * 128 + qcol] = l;
        }
    }
}

// ------------- combine partials: sum chunks, normalize, -> attn_bf -------------
__global__ __launch_bounds__(256) void combine_kernel(const float* __restrict__ part_O,
                                                      const float* __restrict__ part_l,
                                                      unsigned short* __restrict__ attn_bf) {
    int Qt = 8 + blockIdx.x;       // 8..31
    int h  = blockIdx.y;
    int nc = (Qt + 8) >> 3;        // 2,3,4 chunks
    int t = threadIdx.x;
    int q = t & 127;
    int dh = (t >> 7) * 32;
    float l = 0.f;
    float acc[32];
#pragma unroll
    for (int d = 0; d < 32; d++) acc[d] = 0.f;
    for (int c = 0; c < nc; c++) {
        int r;
        if (Qt < 16)      r = 2 * (Qt - 8) + c;
        else if (Qt < 24) r = 16 + 3 * (Qt - 16) + c;
        else              r = 40 + 4 * (Qt - 24) + c;
        int uid = h * 72 + (71 - r);
        l += part_l[uid * 128 + q];
        const float* po = part_O + (size_t)uid * 8192 + (size_t)dh * 128 + q;
#pragma unroll
        for (int d = 0; d < 32; d++) acc[d] += po[d * 128];
    }
    float inv = 1.0f / l;
    unsigned short* op = attn_bf + (size_t)(Qt * 128 + q) * D_MODEL + h * 64 + dh;
#pragma unroll
    for (int d = 0; d < 32; d++) op[d] = f2bf(acc[d] * inv);
}

extern "C" void kernel_launch(void* const* d_in, const int* in_sizes, int n_in,
                              void* d_out, int out_size, void* d_ws, size_t ws_size,
                              hipStream_t stream) {
    const float* x     = (const float*)d_in[0];
    const float* w_qkv = (const float*)d_in[1];
    const float* w_out = (const float*)d_in[2];
    const float* ln_g  = (const float*)d_in[3];
    const float* ln_b  = (const float*)d_in[4];

    float* out   = (float*)d_out;                       // [4096,1024]
    float* out_k = (float*)d_out + 4194304;             // [16,4096,64]
    float* out_v = (float*)d_out + 8388608;             // [16,4096,64]

    char* ws = (char*)d_ws;
    const size_t MiB = 1048576;
    float*          qkv_f   = (float*)(ws);                    // [4096,3072] fp32   @0..48 (dead after rope)
    unsigned short* h_bf    = (unsigned short*)(ws + 48*MiB);  // bf16 @48..56 (dead after gemm1)
    unsigned short* wqkvT   = (unsigned short*)(ws + 56*MiB);  // bf16 @56..62 (dead after gemm1)
    unsigned short* q_bf    = (unsigned short*)(ws + 48*MiB);  // [16,4096,64] bf16  @48..56
    unsigned short* k_bf    = (unsigned short*)(ws + 56*MiB);  // [16,4096,64] bf16  @56..64
    unsigned short* vt_bf   = (unsigned short*)(ws + 64*MiB);  // [16,64,4096] bf16  @64..72
    unsigned short* attn_bf = (unsigned short*)(ws);           // [4096,1024] bf16   @0..8
    float*          part_l  = (float*)(ws + 8*MiB);            // [1152][128] fp32   @8..8.6
    float*          part_O  = (float*)(ws + 9*MiB);            // [1152][64][128]    @9..46.7
    unsigned short* woutT   = (unsigned short*)(ws + 72*MiB);  // [1024,1024] bf16   @72..74

    transpose_cvt<<<dim3(16, 48), 256, 0, stream>>>(w_qkv, wqkvT, D_MODEL, QKV_COLS);
    transpose_cvt<<<dim3(16, 16), 256, 0, stream>>>(w_out, woutT, D_MODEL, D_MODEL);
    ln_kernel<<<N_SEQ, 256, 0, stream>>>(x, ln_g, ln_b, h_bf);
    gemm_bt128<<<dim3(32, 24), 256, 0, stream>>>(h_bf, wqkvT, qkv_f, N_SEQ, QKV_COLS, D_MODEL);
    rope_cache_kernel<<<dim3(64, 16), 256, 0, stream>>>(qkv_f, out_k, out_v, q_bf, k_bf, vt_bf);
    flash_mfma<<<1280, 256, 0, stream>>>(q_bf, k_bf, vt_bf, attn_bf, part_O, part_l);
    combine_kernel<<<dim3(24, 16), 256, 0, stream>>>(part_O, part_l, attn_bf);
    gemm_bt128<<<dim3(32, 8), 256, 0, stream>>>(attn_bf, woutT, out, N_SEQ, D_MODEL, D_MODEL);
}